// Round 16
// baseline (247.131 us; speedup 1.0000x reference)
//
#include <hip/hip_runtime.h>

#define N_NODES 100000
#define NOCT 8
#define SUBCAP 1280   // per-(bucket,octant) slab; mean 1020, sigma~32 -> 8-sigma
#define NCELL (196 * NOCT)

// ---- bf16 helpers (manual, RNE) -------------------------------------------
__device__ __forceinline__ unsigned short f2bf_rn(float f) {
    unsigned int b = __float_as_uint(f);
    b += 0x7fffu + ((b >> 16) & 1u);
    return (unsigned short)(b >> 16);
}
__device__ __forceinline__ float bf_lo(unsigned int u) { return __uint_as_float(u << 16); }
__device__ __forceinline__ float bf_hi(unsigned int u) { return __uint_as_float(u & 0xffff0000u); }

typedef int v4i __attribute__((ext_vector_type(4)));  // native vec for nt-load

// ============ init: cursor[cell] = cell*SUBCAP =============================
__global__ __launch_bounds__(256) void initcur_kernel(unsigned int* __restrict__ cursor) {
    int i = blockIdx.x * 256 + threadIdx.x;
    if (i < NCELL) cursor[i] = (unsigned int)i * SUBCAP;
}

// == bin: edges -> per-(bucket, src-octant) sub-slabs. Entry: src|doff<<17 ==
// Octant split means build can emit each row's srcs octant-sorted -> all
// resident agg waves sweep src space in lockstep -> higher L2 hit on gathers.
__global__ __launch_bounds__(256) void bin_kernel(const int* __restrict__ ei, int E,
                                                  unsigned int* __restrict__ cursor,
                                                  unsigned int* __restrict__ binned) {
    __shared__ unsigned int cnt[NCELL];
    __shared__ unsigned int cur[NCELL];
    int t = threadIdx.x;
    for (int i = t; i < NCELL; i += 256) cnt[i] = 0;
    __syncthreads();
    int base = blockIdx.x * 4096;
    unsigned int pk[16];
    unsigned int ck[16];
    bool vec = ((E & 3) == 0);
#pragma unroll
    for (int k = 0; k < 4; ++k) {
        int e = base + (k * 256 + t) * 4;
        if (vec && e + 3 < E) {
            v4i s4 = __builtin_nontemporal_load((const v4i*)(ei + e));
            v4i d4 = __builtin_nontemporal_load((const v4i*)(ei + E + e));
            int ss[4] = {s4.x, s4.y, s4.z, s4.w};
            int dd[4] = {d4.x, d4.y, d4.z, d4.w};
#pragma unroll
            for (int q = 0; q < 4; ++q) {
                unsigned int cell = (((unsigned int)dd[q] >> 9) << 3) +
                                    ((unsigned int)ss[q] / 12500u);
                pk[k * 4 + q] = (unsigned int)ss[q] | (((unsigned int)dd[q] & 511u) << 17);
                ck[k * 4 + q] = cell;
                atomicAdd(&cnt[cell], 1u);
            }
        } else {
#pragma unroll
            for (int q = 0; q < 4; ++q) {
                int eq = e + q;
                if (eq < E) {
                    int s = ei[eq], d = ei[E + eq];
                    unsigned int cell = (((unsigned int)d >> 9) << 3) +
                                        ((unsigned int)s / 12500u);
                    pk[k * 4 + q] = (unsigned int)s | (((unsigned int)d & 511u) << 17);
                    ck[k * 4 + q] = cell;
                    atomicAdd(&cnt[cell], 1u);
                } else {
                    ck[k * 4 + q] = 0xFFFFFFFFu;
                }
            }
        }
    }
    __syncthreads();
    for (int i = t; i < NCELL; i += 256)
        if (cnt[i] > 0) cur[i] = atomicAdd(&cursor[i], cnt[i]);
    __syncthreads();
#pragma unroll
    for (int k = 0; k < 16; ++k) {
        if (ck[k] != 0xFFFFFFFFu) {
            unsigned int pos = atomicAdd(&cur[ck[k]], 1u);
            binned[pos] = pk[k];
        }
    }
}

// ==== cscan: per-bucket totals from 8 cells; exclusive scan -> CSR bases ===
__global__ __launch_bounds__(256) void cscan_kernel(const unsigned int* __restrict__ cursor,
                                                    int nb, int E,
                                                    unsigned int* __restrict__ bucket_base) {
    __shared__ unsigned int s[256];
    int t = threadIdx.x;
    unsigned int v = 0;
    if (t < nb) {
#pragma unroll
        for (int o = 0; o < NOCT; ++o) {
            int cell = t * NOCT + o;
            v += cursor[cell] - (unsigned int)cell * SUBCAP;
        }
    }
    s[t] = v; __syncthreads();
    for (int off = 1; off < 256; off <<= 1) {
        unsigned int x = s[t];
        unsigned int y = (t >= off) ? s[t - off] : 0u;
        __syncthreads();
        s[t] = x + y;
        __syncthreads();
    }
    if (t < nb) bucket_base[t] = s[t] - v;
    if (t == 0) bucket_base[nb] = (unsigned int)E;
}

// == build: per-bucket hist+scan -> row_start/dinv; octant-ordered scatter ==
// Scatter walks sub-slabs oct 0..7 with a barrier between -> each row's srcs
// land in octant-sorted order (the L2-sweep property for the agg kernels).
__global__ __launch_bounds__(512) void build_kernel(const unsigned int* __restrict__ binned,
                                                    const unsigned int* __restrict__ cursor,
                                                    const unsigned int* __restrict__ bucket_base,
                                                    float* __restrict__ dinv,
                                                    int* __restrict__ row_start,
                                                    int* __restrict__ srcs, int N, int E) {
    __shared__ unsigned int cnt[512];
    __shared__ unsigned int sc[512];
    __shared__ int cur[512];
    int t = threadIdx.x;
    cnt[t] = 0;
    int obase = (int)bucket_base[blockIdx.x];
    __syncthreads();
#pragma unroll
    for (int oct = 0; oct < NOCT; ++oct) {
        int cell = blockIdx.x * NOCT + oct;
        int bbeg = cell * SUBCAP;
        int bend = (int)cursor[cell];
        for (int i = bbeg + t; i < bend; i += 512)
            atomicAdd(&cnt[binned[i] >> 17], 1u);
    }
    __syncthreads();
    unsigned int v = cnt[t];
    sc[t] = v; __syncthreads();
    for (int off = 1; off < 512; off <<= 1) {   // inclusive Hillis-Steele
        unsigned int x = sc[t];
        unsigned int y = (t >= off) ? sc[t - off] : 0u;
        __syncthreads();
        sc[t] = x + y;
        __syncthreads();
    }
    int excl = obase + (int)(sc[t] - v);
    int node = (blockIdx.x << 9) + t;
    if (node < N) {
        row_start[node] = excl;
        dinv[node] = rsqrtf((float)v + 1.0f);
    }
    cur[t] = excl;
    if (blockIdx.x == 0 && t == 0) row_start[N] = E;
    __syncthreads();
#pragma unroll
    for (int oct = 0; oct < NOCT; ++oct) {
        int cell = blockIdx.x * NOCT + oct;
        int bbeg = cell * SUBCAP;
        int bend = (int)cursor[cell];
        for (int i = bbeg + t; i < bend; i += 512) {
            unsigned int u = binned[i];
            int slot = atomicAdd(&cur[u >> 17], 1);
            srcs[slot] = (int)(u & 0x1FFFFu);
        }
        __syncthreads();   // octant ordering within each row
    }
}

// ============ GEMM1: h1s[N,64](bf16) = (x @ W1) * dinv[row] ================
__global__ __launch_bounds__(256) void gemm1_kernel(
    const float* __restrict__ x, const float* __restrict__ W,
    const float* __restrict__ dinv,
    unsigned short* __restrict__ h1b, int N) {
    __shared__ float4 Ws4[128 * 16];     // W row-major k x 64 (16 float4/row)
    __shared__ float4 xs4[64 * 33];      // 64 rows x 132 floats (pad 4)
    int tid = threadIdx.x;
    const float4* W4 = (const float4*)W;
#pragma unroll
    for (int i = 0; i < 8; ++i) Ws4[tid + 256 * i] = W4[tid + 256 * i];
    int row0 = blockIdx.x * 64;
    const float4* x4 = (const float4*)x;
#pragma unroll
    for (int i = 0; i < 8; ++i) {
        int idx = tid + 256 * i;             // 2048 float4 = 64 rows x 32
        int r = idx >> 5, c = idx & 31;
        int gr = row0 + r;
        float4 v;
        if (gr < N) v = x4[(size_t)gr * 32 + c];
        else { v.x = v.y = v.z = v.w = 0.f; }
        xs4[r * 33 + c] = v;
    }
    __syncthreads();
    int tc = tid & 15;        // col group: cols tc*4..tc*4+3
    int tr = tid >> 4;        // row group: rows tr*4..tr*4+3
    float4 acc[4];
#pragma unroll
    for (int rr = 0; rr < 4; ++rr) { acc[rr].x = 0.f; acc[rr].y = 0.f; acc[rr].z = 0.f; acc[rr].w = 0.f; }
#pragma unroll 2
    for (int k4 = 0; k4 < 32; ++k4) {
        float4 xr[4], w[4];
#pragma unroll
        for (int rr = 0; rr < 4; ++rr) xr[rr] = xs4[(tr * 4 + rr) * 33 + k4];
#pragma unroll
        for (int kk = 0; kk < 4; ++kk) w[kk] = Ws4[(k4 * 4 + kk) * 16 + tc];
#pragma unroll
        for (int rr = 0; rr < 4; ++rr) {
            acc[rr].x += xr[rr].x * w[0].x; acc[rr].y += xr[rr].x * w[0].y;
            acc[rr].z += xr[rr].x * w[0].z; acc[rr].w += xr[rr].x * w[0].w;
            acc[rr].x += xr[rr].y * w[1].x; acc[rr].y += xr[rr].y * w[1].y;
            acc[rr].z += xr[rr].y * w[1].z; acc[rr].w += xr[rr].y * w[1].w;
            acc[rr].x += xr[rr].z * w[2].x; acc[rr].y += xr[rr].z * w[2].y;
            acc[rr].z += xr[rr].z * w[2].z; acc[rr].w += xr[rr].z * w[2].w;
            acc[rr].x += xr[rr].w * w[3].x; acc[rr].y += xr[rr].w * w[3].y;
            acc[rr].z += xr[rr].w * w[3].z; acc[rr].w += xr[rr].w * w[3].w;
        }
    }
#pragma unroll
    for (int rr = 0; rr < 4; ++rr) {
        int r = row0 + tr * 4 + rr;
        if (r < N) {
            float di = dinv[r];
            ushort4 o;
            o.x = f2bf_rn(acc[rr].x * di); o.y = f2bf_rn(acc[rr].y * di);
            o.z = f2bf_rn(acc[rr].z * di); o.w = f2bf_rn(acc[rr].w * di);
            *(ushort4*)(h1b + (size_t)r * 64 + tc * 4) = o;   // 8B coalesced
        }
    }
}

// ============ Aggregation 1 (+bias+relu) fused with GEMM2 ==================
// r9/r14-proven form: 32 lanes/node (4B bf16-pairs), 8 nodes/block,
// batch-16/8/4 deep prefetch. VGPR 32 -> occupancy ~68%.
__global__ __launch_bounds__(256) void agg1_kernel(
    const unsigned int* __restrict__ h1u,   // [N,32] bf16-pairs (pre-scaled)
    const int* __restrict__ srcs,
    const int* __restrict__ row_start, const float* __restrict__ dinv,
    const float* __restrict__ b1, const float* __restrict__ W2,
    unsigned short* __restrict__ h2b, int N) {
    __shared__ float W2s[64 * 32];
    __shared__ float hr[8][64];
    int tid = threadIdx.x;
    const float4* W24 = (const float4*)W2;
    float4* W2s4 = (float4*)W2s;
#pragma unroll
    for (int i = 0; i < 2; ++i) W2s4[tid + 256 * i] = W24[tid + 256 * i];
    __syncthreads();
    int nib = tid >> 5;           // node-in-block 0..7
    int jp = tid & 31;            // feature pair
    int d = blockIdx.x * 8 + nib;
    if (d >= N) return;           // no barriers after this point
    float di = dinv[d];
    float2 bias = ((const float2*)b1)[jp];
    unsigned int su = h1u[(size_t)d * 32 + jp];
    int beg = row_start[d], end = row_start[d + 1];
    float a0 = bf_lo(su);         // self-loop term (pre-scaled)
    float a1 = bf_hi(su);
    int e = beg;
    for (; e + 16 <= end; e += 16) {   // batch-16: 16 gathers in flight
        int c[16];
#pragma unroll
        for (int k = 0; k < 16; ++k) c[k] = srcs[e + k];
        unsigned int u[16];
#pragma unroll
        for (int k = 0; k < 16; ++k) u[k] = h1u[(size_t)c[k] * 32 + jp];
#pragma unroll
        for (int k = 0; k < 16; ++k) { a0 += bf_lo(u[k]); a1 += bf_hi(u[k]); }
    }
    if (e + 8 <= end) {
        int c[8];
#pragma unroll
        for (int k = 0; k < 8; ++k) c[k] = srcs[e + k];
        unsigned int u[8];
#pragma unroll
        for (int k = 0; k < 8; ++k) u[k] = h1u[(size_t)c[k] * 32 + jp];
#pragma unroll
        for (int k = 0; k < 8; ++k) { a0 += bf_lo(u[k]); a1 += bf_hi(u[k]); }
        e += 8;
    }
    if (e + 4 <= end) {
        int c[4];
#pragma unroll
        for (int k = 0; k < 4; ++k) c[k] = srcs[e + k];
        unsigned int u[4];
#pragma unroll
        for (int k = 0; k < 4; ++k) u[k] = h1u[(size_t)c[k] * 32 + jp];
#pragma unroll
        for (int k = 0; k < 4; ++k) { a0 += bf_lo(u[k]); a1 += bf_hi(u[k]); }
        e += 4;
    }
    for (; e < end; ++e) {
        unsigned int u0 = h1u[(size_t)srcs[e] * 32 + jp];
        a0 += bf_lo(u0); a1 += bf_hi(u0);
    }
    float h0 = fmaxf(a0 * di + bias.x, 0.f);
    float h1v = fmaxf(a1 * di + bias.y, 0.f);
    hr[nib][2 * jp] = h0;             // intra-wave LDS RAW, lgkmcnt-ordered
    hr[nib][2 * jp + 1] = h1v;
    const float* hrw = hr[nib];
    float p = 0.f;
#pragma unroll 8
    for (int k = 0; k < 64; ++k)
        p += hrw[k] * W2s[k * 32 + jp];
    h2b[(size_t)d * 32 + jp] = f2bf_rn(p * di);   // pre-scale for layer 2
}

// ===================== Aggregation 2 -> out (final layer) ==================
// 8 lanes/node, uint2 feature-quads, batch-8/4 prefetch (r14-proven form).
__global__ __launch_bounds__(256) void agg2_kernel(
    const uint2* __restrict__ h2v,          // [N,8] bf16-quads (pre-scaled)
    const int* __restrict__ srcs,
    const int* __restrict__ row_start, const float* __restrict__ dinv,
    const float* __restrict__ b2, float* __restrict__ out, int N) {
    int t = blockIdx.x * 256 + threadIdx.x;
    int d = t >> 3;
    int jp = t & 7;               // feature quad (feats 4jp..4jp+3)
    if (d >= N) return;
    float di = dinv[d];
    float4 bias = ((const float4*)b2)[jp];
    uint2 su = h2v[(size_t)d * 8 + jp];
    int beg = row_start[d], end = row_start[d + 1];
    float a0 = bf_lo(su.x), a1 = bf_hi(su.x);
    float a2 = bf_lo(su.y), a3 = bf_hi(su.y);
    int e = beg;
    for (; e + 8 <= end; e += 8) {     // batch-8: 8 uint2 gathers in flight
        int c[8];
#pragma unroll
        for (int k = 0; k < 8; ++k) c[k] = srcs[e + k];
        uint2 u[8];
#pragma unroll
        for (int k = 0; k < 8; ++k) u[k] = h2v[(size_t)c[k] * 8 + jp];
#pragma unroll
        for (int k = 0; k < 8; ++k) {
            a0 += bf_lo(u[k].x); a1 += bf_hi(u[k].x);
            a2 += bf_lo(u[k].y); a3 += bf_hi(u[k].y);
        }
    }
    if (e + 4 <= end) {
        int c[4];
#pragma unroll
        for (int k = 0; k < 4; ++k) c[k] = srcs[e + k];
        uint2 u[4];
#pragma unroll
        for (int k = 0; k < 4; ++k) u[k] = h2v[(size_t)c[k] * 8 + jp];
#pragma unroll
        for (int k = 0; k < 4; ++k) {
            a0 += bf_lo(u[k].x); a1 += bf_hi(u[k].x);
            a2 += bf_lo(u[k].y); a3 += bf_hi(u[k].y);
        }
        e += 4;
    }
    for (; e < end; ++e) {
        uint2 u0 = h2v[(size_t)srcs[e] * 8 + jp];
        a0 += bf_lo(u0.x); a1 += bf_hi(u0.x);
        a2 += bf_lo(u0.y); a3 += bf_hi(u0.y);
    }
    float4 r;
    r.x = a0 * di + bias.x;
    r.y = a1 * di + bias.y;
    r.z = a2 * di + bias.z;
    r.w = a3 * di + bias.w;
    ((float4*)(out + (size_t)d * 32))[jp] = r;   // 8 lanes x 16B = 128B/row
}

extern "C" void kernel_launch(void* const* d_in, const int* in_sizes, int n_in,
                              void* d_out, int out_size, void* d_ws, size_t ws_size,
                              hipStream_t stream) {
    const float* x  = (const float*)d_in[0];
    const int*   ei = (const int*)d_in[1];
    const float* W1 = (const float*)d_in[2];
    const float* b1 = (const float*)d_in[3];
    const float* W2 = (const float*)d_in[4];
    const float* b2 = (const float*)d_in[5];
    float* out = (float*)d_out;

    const int N = N_NODES;
    const int E = in_sizes[1] / 2;
    const int NB = (N + 511) / 512;          // 196 buckets
    const int EB = (E + 4095) / 4096;        // 391 edge blocks

    // Workspace: srcs[E]i32 | binned[NCELL*SUBCAP]u32 | h1b | h2b | dinv |
    // row_start[N+1] | cursor[NCELL] | bucket_base[260]   (~35 MB)
    char* p = (char*)d_ws;
    int* srcs = (int*)p;                      p += (size_t)E * 4;
    unsigned int* binned = (unsigned int*)p;  p += (size_t)NCELL * SUBCAP * 4;
    unsigned short* h1b = (unsigned short*)p; p += (size_t)N * 64 * 2;
    unsigned short* h2b = (unsigned short*)p; p += (size_t)N * 32 * 2;
    float* dinv = (float*)p;                  p += (size_t)N * 4;
    int* row_start = (int*)p;                 p += (size_t)(N + 1) * 4;
    unsigned int* cursor = (unsigned int*)p;  p += ((NCELL + 63) / 64) * 64 * 4;
    unsigned int* bucket_base = (unsigned int*)p;

    initcur_kernel<<<(NCELL + 255) / 256, 256, 0, stream>>>(cursor);
    bin_kernel<<<EB, 256, 0, stream>>>(ei, E, cursor, binned);
    cscan_kernel<<<1, 256, 0, stream>>>(cursor, NB, E, bucket_base);
    build_kernel<<<NB, 512, 0, stream>>>(binned, cursor, bucket_base, dinv,
                                         row_start, srcs, N, E);

    gemm1_kernel<<<(N + 63) / 64, 256, 0, stream>>>(x, W1, dinv, h1b, N);
    agg1_kernel<<<(N + 7) / 8, 256, 0, stream>>>((const unsigned int*)h1b, srcs, row_start,
                                                 dinv, b1, W2, h2b, N);
    agg2_kernel<<<(N * 8 + 255) / 256, 256, 0, stream>>>((const uint2*)h2b, srcs,
                                                         row_start, dinv, b2, out, N);
}

// Round 17
// 221.739 us; speedup vs baseline: 1.1145x; 1.1145x over previous
//
#include <hip/hip_runtime.h>

#define N_NODES 100000
#define CAP 10240   // per-bucket slab capacity; mean 8192, sigma~90 -> 22-sigma

// ---- bf16 helpers (manual, RNE) -------------------------------------------
__device__ __forceinline__ unsigned short f2bf_rn(float f) {
    unsigned int b = __float_as_uint(f);
    b += 0x7fffu + ((b >> 16) & 1u);
    return (unsigned short)(b >> 16);
}
__device__ __forceinline__ float bf_lo(unsigned int u) { return __uint_as_float(u << 16); }
__device__ __forceinline__ float bf_hi(unsigned int u) { return __uint_as_float(u & 0xffff0000u); }

typedef int v4i __attribute__((ext_vector_type(4)));  // native vec for nt-load

// ============ init: cursor[b] = b*CAP (replaces memset + bcount/bscan) =====
__global__ __launch_bounds__(256) void initcur_kernel(unsigned int* __restrict__ cursor) {
    int t = threadIdx.x;
    cursor[t] = (unsigned int)t * CAP;
}

// ====== bin: group edges into fixed-capacity per-bucket slabs (1 pass) =====
// Entry: src (17b) | dst&511 (9b)<<17.  Vectorized 16B nt edge reads.
__global__ __launch_bounds__(256) void bin_kernel(const int* __restrict__ ei, int E,
                                                  unsigned int* __restrict__ cursor,
                                                  unsigned int* __restrict__ binned) {
    __shared__ unsigned int cnt[256];
    __shared__ unsigned int cur[256];
    int t = threadIdx.x;
    cnt[t] = 0;
    __syncthreads();
    int base = blockIdx.x * 4096;
    unsigned int pk[16];
    unsigned int bk[16];
    bool vec = ((E & 3) == 0);
#pragma unroll
    for (int k = 0; k < 4; ++k) {
        int e = base + (k * 256 + t) * 4;
        if (vec && e + 3 < E) {
            v4i s4 = __builtin_nontemporal_load((const v4i*)(ei + e));
            v4i d4 = __builtin_nontemporal_load((const v4i*)(ei + E + e));
            int ss[4] = {s4.x, s4.y, s4.z, s4.w};
            int dd[4] = {d4.x, d4.y, d4.z, d4.w};
#pragma unroll
            for (int q = 0; q < 4; ++q) {
                unsigned int b = (unsigned int)dd[q] >> 9;
                pk[k * 4 + q] = (unsigned int)ss[q] | (((unsigned int)dd[q] & 511u) << 17);
                bk[k * 4 + q] = b;
                atomicAdd(&cnt[b], 1u);
            }
        } else {
#pragma unroll
            for (int q = 0; q < 4; ++q) {
                int eq = e + q;
                if (eq < E) {
                    int s = ei[eq], d = ei[E + eq];
                    unsigned int b = (unsigned int)d >> 9;
                    pk[k * 4 + q] = (unsigned int)s | (((unsigned int)d & 511u) << 17);
                    bk[k * 4 + q] = b;
                    atomicAdd(&cnt[b], 1u);
                } else {
                    bk[k * 4 + q] = 0xFFFFFFFFu;
                }
            }
        }
    }
    __syncthreads();
    if (cnt[t] > 0) cur[t] = atomicAdd(&cursor[t], cnt[t]);
    __syncthreads();
#pragma unroll
    for (int k = 0; k < 16; ++k) {
        if (bk[k] != 0xFFFFFFFFu) {
            unsigned int pos = atomicAdd(&cur[bk[k]], 1u);
            binned[pos] = pk[k];
        }
    }
}

// ==== cscan: counts = cursor[b]-b*CAP; exclusive scan -> global CSR bases ==
__global__ __launch_bounds__(256) void cscan_kernel(const unsigned int* __restrict__ cursor,
                                                    int nb, int E,
                                                    unsigned int* __restrict__ bucket_base) {
    __shared__ unsigned int s[256];
    int t = threadIdx.x;
    unsigned int v = (t < nb) ? (cursor[t] - (unsigned int)t * CAP) : 0u;
    s[t] = v; __syncthreads();
    for (int off = 1; off < 256; off <<= 1) {
        unsigned int x = s[t];
        unsigned int y = (t >= off) ? s[t - off] : 0u;
        __syncthreads();
        s[t] = x + y;
        __syncthreads();
    }
    if (t < nb) bucket_base[t] = s[t] - v;
    if (t == 0) bucket_base[nb] = (unsigned int)E;
}

// == build: per-bucket LDS hist + scan -> row_start/dinv, then scatter srcs ==
__global__ __launch_bounds__(512) void build_kernel(const unsigned int* __restrict__ binned,
                                                    const unsigned int* __restrict__ cursor,
                                                    const unsigned int* __restrict__ bucket_base,
                                                    float* __restrict__ dinv,
                                                    int* __restrict__ row_start,
                                                    int* __restrict__ srcs, int N, int E) {
    __shared__ unsigned int cnt[512];
    __shared__ unsigned int sc[512];
    __shared__ int cur[512];
    int t = threadIdx.x;
    cnt[t] = 0;
    int bbeg = blockIdx.x * CAP;               // binned slab range
    int bend = (int)cursor[blockIdx.x];
    int obase = (int)bucket_base[blockIdx.x];  // global CSR offset base
    __syncthreads();
    for (int i = bbeg + t; i < bend; i += 512)
        atomicAdd(&cnt[binned[i] >> 17], 1u);
    __syncthreads();
    unsigned int v = cnt[t];
    sc[t] = v; __syncthreads();
    for (int off = 1; off < 512; off <<= 1) {   // inclusive Hillis-Steele
        unsigned int x = sc[t];
        unsigned int y = (t >= off) ? sc[t - off] : 0u;
        __syncthreads();
        sc[t] = x + y;
        __syncthreads();
    }
    int excl = obase + (int)(sc[t] - v);
    int node = (blockIdx.x << 9) + t;
    if (node < N) {
        row_start[node] = excl;
        dinv[node] = rsqrtf((float)v + 1.0f);
    }
    cur[t] = excl;
    if (blockIdx.x == 0 && t == 0) row_start[N] = E;
    __syncthreads();
    for (int i = bbeg + t; i < bend; i += 512) {
        unsigned int u = binned[i];
        int slot = atomicAdd(&cur[u >> 17], 1);
        srcs[slot] = (int)(u & 0x1FFFFu);
    }
}

// ============ GEMM1: h1s[N,64](bf16) = (x @ W1) * dinv[row] ================
// 64-row tile, 4x4 register blocking, K-CHUNKED staging (64 k per phase):
// LDS 33.8 KB (was 66.5) -> 4 blocks/CU, 50% occupancy (was 2 blocks, 16% --
// r16 profile showed gemm1 latency-bound at 48 us, VALUBusy 28%).
// Bank check (per wave): xs stride 17 float4 -> tr-delta 272 dwords = 16 mod
// 32 -> 2-way (free, m136); Ws tc-consecutive b128 -> 2-way (free).
__global__ __launch_bounds__(256) void gemm1_kernel(
    const float* __restrict__ x, const float* __restrict__ W,
    const float* __restrict__ dinv,
    unsigned short* __restrict__ h1b, int N) {
    __shared__ float4 Ws4[64 * 16];      // k-chunk of W: 64 k x 64 cols
    __shared__ float4 xs4[64 * 17];      // 64 rows x (16 float4 + 1 pad)
    int tid = threadIdx.x;
    int row0 = blockIdx.x * 64;
    int tc = tid & 15;        // col group: cols tc*4..tc*4+3
    int tr = tid >> 4;        // row group: rows tr*4..tr*4+3
    const float4* W4 = (const float4*)W;
    const float4* x4 = (const float4*)x;
    float4 acc[4];
#pragma unroll
    for (int rr = 0; rr < 4; ++rr) { acc[rr].x = 0.f; acc[rr].y = 0.f; acc[rr].z = 0.f; acc[rr].w = 0.f; }
#pragma unroll
    for (int ch = 0; ch < 2; ++ch) {
#pragma unroll
        for (int i = 0; i < 4; ++i)               // W rows ch*64..+64
            Ws4[tid + 256 * i] = W4[ch * 1024 + tid + 256 * i];
#pragma unroll
        for (int i = 0; i < 4; ++i) {             // x cols ch*64..+64
            int idx = tid + 256 * i;              // 1024 float4 = 64 rows x 16
            int r = idx >> 4, c = idx & 15;
            int gr = row0 + r;
            float4 v;
            if (gr < N) v = x4[(size_t)gr * 32 + ch * 16 + c];
            else { v.x = v.y = v.z = v.w = 0.f; }
            xs4[r * 17 + c] = v;
        }
        __syncthreads();
#pragma unroll 2
        for (int k4 = 0; k4 < 16; ++k4) {
            float4 xr[4], w[4];
#pragma unroll
            for (int rr = 0; rr < 4; ++rr) xr[rr] = xs4[(tr * 4 + rr) * 17 + k4];
#pragma unroll
            for (int kk = 0; kk < 4; ++kk) w[kk] = Ws4[(k4 * 4 + kk) * 16 + tc];
#pragma unroll
            for (int rr = 0; rr < 4; ++rr) {
                acc[rr].x += xr[rr].x * w[0].x; acc[rr].y += xr[rr].x * w[0].y;
                acc[rr].z += xr[rr].x * w[0].z; acc[rr].w += xr[rr].x * w[0].w;
                acc[rr].x += xr[rr].y * w[1].x; acc[rr].y += xr[rr].y * w[1].y;
                acc[rr].z += xr[rr].y * w[1].z; acc[rr].w += xr[rr].y * w[1].w;
                acc[rr].x += xr[rr].z * w[2].x; acc[rr].y += xr[rr].z * w[2].y;
                acc[rr].z += xr[rr].z * w[2].z; acc[rr].w += xr[rr].z * w[2].w;
                acc[rr].x += xr[rr].w * w[3].x; acc[rr].y += xr[rr].w * w[3].y;
                acc[rr].z += xr[rr].w * w[3].z; acc[rr].w += xr[rr].w * w[3].w;
            }
        }
        __syncthreads();
    }
#pragma unroll
    for (int rr = 0; rr < 4; ++rr) {
        int r = row0 + tr * 4 + rr;
        if (r < N) {
            float di = dinv[r];
            ushort4 o;
            o.x = f2bf_rn(acc[rr].x * di); o.y = f2bf_rn(acc[rr].y * di);
            o.z = f2bf_rn(acc[rr].z * di); o.w = f2bf_rn(acc[rr].w * di);
            *(ushort4*)(h1b + (size_t)r * 64 + tc * 4) = o;   // 8B coalesced
        }
    }
}

// ============ Aggregation 1 (+bias+relu) fused with GEMM2 ==================
// r9/r14-proven form: 32 lanes/node (4B bf16-pairs), 8 nodes/block,
// batch-16/8/4 deep prefetch. VGPR 32 -> occupancy ~68%.
__global__ __launch_bounds__(256) void agg1_kernel(
    const unsigned int* __restrict__ h1u,   // [N,32] bf16-pairs (pre-scaled)
    const int* __restrict__ srcs,
    const int* __restrict__ row_start, const float* __restrict__ dinv,
    const float* __restrict__ b1, const float* __restrict__ W2,
    unsigned short* __restrict__ h2b, int N) {
    __shared__ float W2s[64 * 32];
    __shared__ float hr[8][64];
    int tid = threadIdx.x;
    const float4* W24 = (const float4*)W2;
    float4* W2s4 = (float4*)W2s;
#pragma unroll
    for (int i = 0; i < 2; ++i) W2s4[tid + 256 * i] = W24[tid + 256 * i];
    __syncthreads();
    int nib = tid >> 5;           // node-in-block 0..7
    int jp = tid & 31;            // feature pair
    int d = blockIdx.x * 8 + nib;
    if (d >= N) return;           // no barriers after this point
    float di = dinv[d];
    float2 bias = ((const float2*)b1)[jp];
    unsigned int su = h1u[(size_t)d * 32 + jp];
    int beg = row_start[d], end = row_start[d + 1];
    float a0 = bf_lo(su);         // self-loop term (pre-scaled)
    float a1 = bf_hi(su);
    int e = beg;
    for (; e + 16 <= end; e += 16) {   // batch-16: 16 gathers in flight
        int c[16];
#pragma unroll
        for (int k = 0; k < 16; ++k) c[k] = srcs[e + k];
        unsigned int u[16];
#pragma unroll
        for (int k = 0; k < 16; ++k) u[k] = h1u[(size_t)c[k] * 32 + jp];
#pragma unroll
        for (int k = 0; k < 16; ++k) { a0 += bf_lo(u[k]); a1 += bf_hi(u[k]); }
    }
    if (e + 8 <= end) {
        int c[8];
#pragma unroll
        for (int k = 0; k < 8; ++k) c[k] = srcs[e + k];
        unsigned int u[8];
#pragma unroll
        for (int k = 0; k < 8; ++k) u[k] = h1u[(size_t)c[k] * 32 + jp];
#pragma unroll
        for (int k = 0; k < 8; ++k) { a0 += bf_lo(u[k]); a1 += bf_hi(u[k]); }
        e += 8;
    }
    if (e + 4 <= end) {
        int c[4];
#pragma unroll
        for (int k = 0; k < 4; ++k) c[k] = srcs[e + k];
        unsigned int u[4];
#pragma unroll
        for (int k = 0; k < 4; ++k) u[k] = h1u[(size_t)c[k] * 32 + jp];
#pragma unroll
        for (int k = 0; k < 4; ++k) { a0 += bf_lo(u[k]); a1 += bf_hi(u[k]); }
        e += 4;
    }
    for (; e < end; ++e) {
        unsigned int u0 = h1u[(size_t)srcs[e] * 32 + jp];
        a0 += bf_lo(u0); a1 += bf_hi(u0);
    }
    float h0 = fmaxf(a0 * di + bias.x, 0.f);
    float h1v = fmaxf(a1 * di + bias.y, 0.f);
    hr[nib][2 * jp] = h0;             // intra-wave LDS RAW, lgkmcnt-ordered
    hr[nib][2 * jp + 1] = h1v;
    const float* hrw = hr[nib];
    float p = 0.f;
#pragma unroll 8
    for (int k = 0; k < 64; ++k)
        p += hrw[k] * W2s[k * 32 + jp];
    h2b[(size_t)d * 32 + jp] = f2bf_rn(p * di);   // pre-scale for layer 2
}

// ===================== Aggregation 2 -> out (final layer) ==================
// 8 lanes/node, uint2 feature-quads, batch-8/4 prefetch (r14-proven form).
__global__ __launch_bounds__(256) void agg2_kernel(
    const uint2* __restrict__ h2v,          // [N,8] bf16-quads (pre-scaled)
    const int* __restrict__ srcs,
    const int* __restrict__ row_start, const float* __restrict__ dinv,
    const float* __restrict__ b2, float* __restrict__ out, int N) {
    int t = blockIdx.x * 256 + threadIdx.x;
    int d = t >> 3;
    int jp = t & 7;               // feature quad (feats 4jp..4jp+3)
    if (d >= N) return;
    float di = dinv[d];
    float4 bias = ((const float4*)b2)[jp];
    uint2 su = h2v[(size_t)d * 8 + jp];
    int beg = row_start[d], end = row_start[d + 1];
    float a0 = bf_lo(su.x), a1 = bf_hi(su.x);
    float a2 = bf_lo(su.y), a3 = bf_hi(su.y);
    int e = beg;
    for (; e + 8 <= end; e += 8) {     // batch-8: 8 uint2 gathers in flight
        int c[8];
#pragma unroll
        for (int k = 0; k < 8; ++k) c[k] = srcs[e + k];
        uint2 u[8];
#pragma unroll
        for (int k = 0; k < 8; ++k) u[k] = h2v[(size_t)c[k] * 8 + jp];
#pragma unroll
        for (int k = 0; k < 8; ++k) {
            a0 += bf_lo(u[k].x); a1 += bf_hi(u[k].x);
            a2 += bf_lo(u[k].y); a3 += bf_hi(u[k].y);
        }
    }
    if (e + 4 <= end) {
        int c[4];
#pragma unroll
        for (int k = 0; k < 4; ++k) c[k] = srcs[e + k];
        uint2 u[4];
#pragma unroll
        for (int k = 0; k < 4; ++k) u[k] = h2v[(size_t)c[k] * 8 + jp];
#pragma unroll
        for (int k = 0; k < 4; ++k) {
            a0 += bf_lo(u[k].x); a1 += bf_hi(u[k].x);
            a2 += bf_lo(u[k].y); a3 += bf_hi(u[k].y);
        }
        e += 4;
    }
    for (; e < end; ++e) {
        uint2 u0 = h2v[(size_t)srcs[e] * 8 + jp];
        a0 += bf_lo(u0.x); a1 += bf_hi(u0.x);
        a2 += bf_lo(u0.y); a3 += bf_hi(u0.y);
    }
    float4 r;
    r.x = a0 * di + bias.x;
    r.y = a1 * di + bias.y;
    r.z = a2 * di + bias.z;
    r.w = a3 * di + bias.w;
    ((float4*)(out + (size_t)d * 32))[jp] = r;   // 8 lanes x 16B = 128B/row
}

extern "C" void kernel_launch(void* const* d_in, const int* in_sizes, int n_in,
                              void* d_out, int out_size, void* d_ws, size_t ws_size,
                              hipStream_t stream) {
    const float* x  = (const float*)d_in[0];
    const int*   ei = (const int*)d_in[1];
    const float* W1 = (const float*)d_in[2];
    const float* b1 = (const float*)d_in[3];
    const float* W2 = (const float*)d_in[4];
    const float* b2 = (const float*)d_in[5];
    float* out = (float*)d_out;

    const int N = N_NODES;
    const int E = in_sizes[1] / 2;
    const int NB = (N + 511) / 512;          // 196 buckets
    const int EB = (E + 4095) / 4096;        // 391 edge blocks

    // Workspace: srcs[E]i32 | binned[NB*CAP]u32 | h1b | h2b | dinv |
    // row_start[N+1] | cursor[256] | bucket_base[260]   (~35 MB)
    char* p = (char*)d_ws;
    int* srcs = (int*)p;                      p += (size_t)E * 4;
    unsigned int* binned = (unsigned int*)p;  p += (size_t)NB * CAP * 4;
    unsigned short* h1b = (unsigned short*)p; p += (size_t)N * 64 * 2;
    unsigned short* h2b = (unsigned short*)p; p += (size_t)N * 32 * 2;
    float* dinv = (float*)p;                  p += (size_t)N * 4;
    int* row_start = (int*)p;                 p += (size_t)(N + 1) * 4;
    unsigned int* cursor = (unsigned int*)p;  p += 256 * 4;
    unsigned int* bucket_base = (unsigned int*)p;

    initcur_kernel<<<1, 256, 0, stream>>>(cursor);
    bin_kernel<<<EB, 256, 0, stream>>>(ei, E, cursor, binned);
    cscan_kernel<<<1, 256, 0, stream>>>(cursor, NB, E, bucket_base);
    build_kernel<<<NB, 512, 0, stream>>>(binned, cursor, bucket_base, dinv,
                                         row_start, srcs, N, E);

    gemm1_kernel<<<(N + 63) / 64, 256, 0, stream>>>(x, W1, dinv, h1b, N);
    agg1_kernel<<<(N + 7) / 8, 256, 0, stream>>>((const unsigned int*)h1b, srcs, row_start,
                                                 dinv, b1, W2, h2b, N);
    agg2_kernel<<<(N * 8 + 255) / 256, 256, 0, stream>>>((const uint2*)h2b, srcs,
                                                         row_start, dinv, b2, out, N);
}